// Round 22
// baseline (82.667 us; speedup 1.0000x reference)
//
#include <hip/hip_runtime.h>
#include <hip/hip_bf16.h>
#include <math.h>

typedef __attribute__((ext_vector_type(8))) short bf16x8;
typedef __attribute__((ext_vector_type(4))) float f32x4;

#define WSTR 68     // G-buffer row stride in shorts (136B): conflict-free frag reads
#define OSTR 80     // out-stage row stride in floats: 3*80 % 32 == 16 -> 2-way (free)

__device__ __forceinline__ short f2bs(float f) {   // fp32 -> bf16 RNE via hw cvt
    union { __hip_bfloat16 b; short s; } u;
    u.b = __float2bfloat16(f);
    return u.s;
}

__device__ __forceinline__ unsigned short f2b_int(float f) {  // prep path (cold)
    union { float f; unsigned int u; } x; x.f = f;
    unsigned int r = x.u + 0x7FFFu + ((x.u >> 16) & 1u);
    return (unsigned short)(r >> 16);
}

// gelu(x) = x*sigmoid(2y), y = 0.7978845608*x*(1+0.044715*x^2)   (tanh-form, hw exp2)
__device__ __forceinline__ float gelu_t(float x) {
    float x2 = x * x;
    float z  = x * fmaf(0.10294324f, x2, 2.3022082f);
    float e  = __builtin_amdgcn_exp2f(z);
    float r  = __builtin_amdgcn_rcpf(1.0f + e);
    return fmaf(x, -r, x);          // x*(1-r)
}

// prep: w1t[n*64+k] = W1cat[k][n]  (n<64: W1top col n, n>=64: W1bot col n-64)
//       w2t[n*64+k] = W2[k][n];  attn = softmax(edge_attn) rows
__global__ void prep_k(const float* __restrict__ W1, const float* __restrict__ W2,
                       const float* __restrict__ ea, unsigned short* __restrict__ w1t,
                       unsigned short* __restrict__ w2t, float* __restrict__ attn)
{
    int gid = blockIdx.x * 256 + threadIdx.x;
    if (gid < 128 * 64) {
        int n = gid >> 6, k = gid & 63;
        float v = (n < 64) ? W1[k * 64 + n] : W1[(64 + k) * 64 + (n - 64)];
        w1t[gid] = f2b_int(v);
    } else if (gid < 12288) {
        int idx = gid - 8192;
        int n = idx >> 6, k = idx & 63;
        w2t[idx] = f2b_int(W2[k * 64 + n]);
    }
    if (gid < 9) {
        int i = gid / 3, j = gid % 3;
        float e0 = ea[i*3+0], e1 = ea[i*3+1], e2 = ea[i*3+2];
        float mx = fmaxf(e0, fmaxf(e1, e2));
        float d = expf(e0-mx) + expf(e1-mx) + expf(e2-mx);
        attn[gid] = expf(ea[i*3+j] - mx) / d;
    }
}

// W1 fragment from swizzled LDS tile: row in [0,128), 16B-granular XOR swizzle
#define WFRAG(Ws, row, ks) \
    (*(const bf16x8*)&(Ws)[(row) * 64 + ((((ks)*32) + q*8) ^ (((row) & 7) << 3))])

__global__ __launch_bounds__(256, 3)
void edge_mfma17(const float* __restrict__ nodes,
                 const unsigned short* __restrict__ w1t,   // 8192 shorts
                 const unsigned short* __restrict__ w2t,   // 4096 shorts
                 const float* __restrict__ attn9,
                 const float* __restrict__ b1,
                 const float* __restrict__ b2,
                 float* __restrict__ out)
{
    __shared__ __align__(16) unsigned short Ws[8192];   // 16 KB swizzled W1
    __shared__ __align__(16) float Un[4 * 12 * OSTR];   // 15.36 KB: G-transpose + out-stage UNION
    // total 31744 B -> 5 blocks/CU. Gw/Ow time-share (per-wave in-order DS pipe).

    const int t = threadIdx.x;
    const int lane = t & 63, wave = t >> 6;
    const int q = lane >> 4, r16 = lane & 15;
    float*          Ow = Un + wave * 12 * OSTR;          // wave-private
    unsigned short* Gw = (unsigned short*)Ow;            // aliased, same bytes

    // ---- stage W1 global -> LDS with 16B-granular XOR swizzle ----
    {
        const ulonglong2* src = (const ulonglong2*)w1t;
        ulonglong2* dst = (ulonglong2*)Ws;
        #pragma unroll
        for (int i = 0; i < 4; ++i) {
            int c = t + i * 256;                          // 1024 chunks
            int n = c >> 3, k8 = c & 7;
            dst[(c & ~7) | (k8 ^ (n & 7))] = src[c];
        }
    }

    // padded tile row r16 -> batch-in-group bA, node-row iA (iA==3 is the dummy row)
    const int bA = r16 >> 2;
    const int iA = r16 & 3;
    const int iAr = (iA == 3) ? 0 : iA;

    // ---- W2 fragments from global (L1-hot; reloads acceptable) ----
    bf16x8 w2f[4][2];
    #pragma unroll
    for (int nt = 0; nt < 4; ++nt)
        #pragma unroll
        for (int ks = 0; ks < 2; ++ks)
            w2f[nt][ks] = *(const bf16x8*)&w2t[(nt*16 + r16) * 64 + ks*32 + q*8];

    // uniform attn weights (SGPR-pinned), per-lane bias slices
    float aw[9];
    #pragma unroll
    for (int i = 0; i < 9; ++i) {
        union { float f; int u; } c; c.f = attn9[i];
        c.u = __builtin_amdgcn_readfirstlane(c.u);
        aw[i] = c.f;
    }
    float b1c[4], b2c[4];
    #pragma unroll
    for (int nt = 0; nt < 4; ++nt) { b1c[nt] = b1[nt*16 + r16]; b2c[nt] = b2[nt*16 + r16]; }

    const int batch0 = blockIdx.x * 64 + wave * 16;

    // ---- phase 0: ALL 16 X loads in flight + cvt (VMEM pipe is otherwise idle) ----
    bf16x8 afr[4][2];
    #pragma unroll
    for (int mt = 0; mt < 4; ++mt) {
        const long rowA = ((long)(batch0 + mt*4 + bA)) * 3 + iAr;
        const f32x4* xp = (const f32x4*)(nodes + rowA * 64 + q * 8);
        f32x4 x0 = xp[0], x1 = xp[1], x2 = xp[8], x3 = xp[9];
        #pragma unroll
        for (int e = 0; e < 4; ++e) {
            afr[mt][0][e]   = f2bs(x0[e]); afr[mt][0][4+e] = f2bs(x1[e]);
            afr[mt][1][e]   = f2bs(x2[e]); afr[mt][1][4+e] = f2bs(x3[e]);
        }
    }

    __syncthreads();   // W1 staged

    #pragma unroll
    for (int mt = 0; mt < 4; ++mt) {
        const int bb = batch0 + mt * 4;                   // this iter's 4 batches

        // ---- GEMM1 + lane-local gelu mix, per 16-col tile; W1 from LDS ----
        #pragma unroll
        for (int nt = 0; nt < 4; ++nt) {
            f32x4 z = {0.f, 0.f, 0.f, 0.f};
            z = __builtin_amdgcn_mfma_f32_16x16x32_bf16(afr[mt][0], WFRAG(Ws, nt*16 + r16, 0), z, 0, 0, 0);
            z = __builtin_amdgcn_mfma_f32_16x16x32_bf16(afr[mt][1], WFRAG(Ws, nt*16 + r16, 1), z, 0, 0, 0);
            f32x4 y = {0.f, 0.f, 0.f, 0.f};
            y = __builtin_amdgcn_mfma_f32_16x16x32_bf16(afr[mt][0], WFRAG(Ws, 64 + nt*16 + r16, 0), y, 0, 0, 0);
            y = __builtin_amdgcn_mfma_f32_16x16x32_bf16(afr[mt][1], WFRAG(Ws, 64 + nt*16 + r16, 1), y, 0, 0, 0);

            // lane holds batch q: u rows z[0..2], v rows y[0..2], col nt*16+r16
            float u0 = z[0] + b1c[nt], u1 = z[1] + b1c[nt], u2 = z[2] + b1c[nt];
            float gg0 = 0.f, gg1 = 0.f, gg2 = 0.f;
            #pragma unroll
            for (int j = 0; j < 3; ++j) {
                float vj = y[j];
                float gl0 = gelu_t(u0 + vj);
                float gl1 = gelu_t(u1 + vj);
                float gl2 = gelu_t(u2 + vj);
                gg0 = fmaf(aw[0*3+j], gl0, gg0);
                gg1 = fmaf(aw[1*3+j], gl1, gg1);
                gg2 = fmaf(aw[2*3+j], gl2, gg2);
            }
            Gw[(q*4 + 0) * WSTR + nt*16 + r16] = (unsigned short)f2bs(gg0);
            Gw[(q*4 + 1) * WSTR + nt*16 + r16] = (unsigned short)f2bs(gg1);
            Gw[(q*4 + 2) * WSTR + nt*16 + r16] = (unsigned short)f2bs(gg2);
        }
        // same-wave DS ordering: compiler emits lgkmcnt before dependent reads

        // ---- GEMM2: A = G via wave-private LDS transpose, B = W2 in regs ----
        bf16x8 gfr0 = *(const bf16x8*)&Gw[r16 * WSTR + q*8];
        bf16x8 gfr1 = *(const bf16x8*)&Gw[r16 * WSTR + 32 + q*8];
        #pragma unroll
        for (int nt = 0; nt < 4; ++nt) {
            f32x4 acc = {0.f, 0.f, 0.f, 0.f};
            acc = __builtin_amdgcn_mfma_f32_16x16x32_bf16(gfr0, w2f[nt][0], acc, 0, 0, 0);
            acc = __builtin_amdgcn_mfma_f32_16x16x32_bf16(gfr1, w2f[nt][1], acc, 0, 0, 0);
            // C: row = q*4 + r (r<3 real), col = nt*16 + r16 -> stage to Ow[q*3+r][col]
            // (overwrites Gw bytes already consumed by the gfr reads — in-order DS)
            #pragma unroll
            for (int r = 0; r < 3; ++r)
                Ow[(q*3 + r) * OSTR + nt*16 + r16] = acc[r] + b2c[nt];
        }

        // ---- coalesced full-line NT stores: 768 consecutive floats per wave-iter ----
        f32x4* gbase = (f32x4*)(out + (long)bb * 192);
        #pragma unroll
        for (int s = 0; s < 3; ++s) {
            int c = lane + 64 * s;
            f32x4 v = *(const f32x4*)&Ow[(c >> 4) * OSTR + (c & 15) * 4];
            __builtin_nontemporal_store(v, gbase + c);
        }
    }
}

extern "C" void kernel_launch(void* const* d_in, const int* in_sizes, int n_in,
                              void* d_out, int out_size, void* d_ws, size_t ws_size,
                              hipStream_t stream)
{
    const float* nodes = (const float*)d_in[0];
    const float* W1    = (const float*)d_in[1];
    const float* b1    = (const float*)d_in[2];
    const float* W2    = (const float*)d_in[3];
    const float* b2    = (const float*)d_in[4];
    const float* ea    = (const float*)d_in[5];
    float* out = (float*)d_out;

    unsigned short* w1t = (unsigned short*)d_ws;          // 8192 shorts (w1cat)
    unsigned short* w2t = w1t + 8192;                     // 4096 shorts (w2)
    float* attn = (float*)(w2t + 4096);                   // 9 floats

    prep_k<<<48, 256, 0, stream>>>(W1, W2, ea, w1t, w2t, attn);

    const int groups = (out_size / 64) / 3 / 64;          // 4096 blocks of 64 batches
    edge_mfma17<<<groups, 256, 0, stream>>>(nodes, w1t, w2t, attn, b1, b2, out);
}

// Round 23
// 81.879 us; speedup vs baseline: 1.0096x; 1.0096x over previous
//
#include <hip/hip_runtime.h>
#include <hip/hip_bf16.h>
#include <math.h>

typedef __attribute__((ext_vector_type(8))) short bf16x8;
typedef __attribute__((ext_vector_type(4))) float f32x4;

#define WSTR 68     // G-buffer row stride in shorts (136B): conflict-free frag reads
#define OSTR 80     // out-stage row stride in floats: 3*80 % 32 == 16 -> 2-way (free)

__device__ __forceinline__ short f2bs(float f) {   // fp32 -> bf16 RNE via hw cvt
    union { __hip_bfloat16 b; short s; } u;
    u.b = __float2bfloat16(f);
    return u.s;
}

__device__ __forceinline__ unsigned short f2b_int(float f) {  // prep path (cold)
    union { float f; unsigned int u; } x; x.f = f;
    unsigned int r = x.u + 0x7FFFu + ((x.u >> 16) & 1u);
    return (unsigned short)(r >> 16);
}

// gelu(x) = x*sigmoid(2y), y = 0.7978845608*x*(1+0.044715*x^2)   (tanh-form, hw exp2)
__device__ __forceinline__ float gelu_t(float x) {
    float x2 = x * x;
    float z  = x * fmaf(0.10294324f, x2, 2.3022082f);
    float e  = __builtin_amdgcn_exp2f(z);
    float r  = __builtin_amdgcn_rcpf(1.0f + e);
    return fmaf(x, -r, x);          // x*(1-r)
}

// prep: w1t[n*64+k] = W1cat[k][n]  (n<64: W1top col n, n>=64: W1bot col n-64)
//       w2t[n*64+k] = W2[k][n];  attn = softmax(edge_attn) rows
__global__ void prep_k(const float* __restrict__ W1, const float* __restrict__ W2,
                       const float* __restrict__ ea, unsigned short* __restrict__ w1t,
                       unsigned short* __restrict__ w2t, float* __restrict__ attn)
{
    int gid = blockIdx.x * 256 + threadIdx.x;
    if (gid < 128 * 64) {
        int n = gid >> 6, k = gid & 63;
        float v = (n < 64) ? W1[k * 64 + n] : W1[(64 + k) * 64 + (n - 64)];
        w1t[gid] = f2b_int(v);
    } else if (gid < 12288) {
        int idx = gid - 8192;
        int n = idx >> 6, k = idx & 63;
        w2t[idx] = f2b_int(W2[k * 64 + n]);
    }
    if (gid < 9) {
        int i = gid / 3, j = gid % 3;
        float e0 = ea[i*3+0], e1 = ea[i*3+1], e2 = ea[i*3+2];
        float mx = fmaxf(e0, fmaxf(e1, e2));
        float d = expf(e0-mx) + expf(e1-mx) + expf(e2-mx);
        attn[gid] = expf(ea[i*3+j] - mx) / d;
    }
}

__global__ __launch_bounds__(256, 3)
void edge_mfma18(const float* __restrict__ nodes,
                 const unsigned short* __restrict__ w1t,   // 8192 shorts
                 const unsigned short* __restrict__ w2t,   // 4096 shorts
                 const float* __restrict__ attn9,
                 const float* __restrict__ b1,
                 const float* __restrict__ b2,
                 float* __restrict__ out)
{
    __shared__ __align__(16) unsigned short Ws[8192];   // 16 KB swizzled W1
    __shared__ __align__(16) float Un[4 * 12 * OSTR];   // 15.36 KB: Gw/Ow time-share union
    // total 31744 B -> 5 blocks/CU. Per-wave in-order DS pipe makes the overlay safe.

    const int t = threadIdx.x;
    const int lane = t & 63, wave = t >> 6;
    const int q = lane >> 4, r16 = lane & 15;
    float*          Ow = Un + wave * 12 * OSTR;          // wave-private
    unsigned short* Gw = (unsigned short*)Ow;            // aliased, same bytes

    // ---- stage W1 global -> LDS with 16B-granular XOR swizzle ----
    {
        const ulonglong2* src = (const ulonglong2*)w1t;
        ulonglong2* dst = (ulonglong2*)Ws;
        #pragma unroll
        for (int i = 0; i < 4; ++i) {
            int c = t + i * 256;                          // 1024 chunks
            int n = c >> 3, k8 = c & 7;
            dst[(c & ~7) | (k8 ^ (n & 7))] = src[c];
        }
    }

    // padded tile row r16 -> batch-in-group bA, node-row iA (iA==3 is the dummy row)
    const int bA = r16 >> 2;
    const int iA = r16 & 3;
    const int iAr = (iA == 3) ? 0 : iA;

    // ---- loop-invariant LDS base pointers: all loop accesses are base + CONSTANT ----
    // W1 frag addr = r16*64 + ((ks*32|q*8) ^ sxor) + nt*1024 (+4096 for V half)
    const int sxor = (r16 & 7) << 3;
    const unsigned short* w1b0 = Ws + r16 * 64 + ((q * 8) ^ sxor);        // ks=0
    const unsigned short* w1b1 = Ws + r16 * 64 + ((32 + q * 8) ^ sxor);   // ks=1
    unsigned short*       gww  = Gw + (q * 4) * WSTR + r16;   // writes: + r*WSTR + nt*16
    const unsigned short* gfrb = Gw + r16 * WSTR + q * 8;     // reads:  + 0, + 32
    float*                oww  = Ow + (q * 3) * OSTR + r16;   // writes: + r*OSTR + nt*16
    const float*          owr  = Ow + q * OSTR + r16 * 4;     // reads:  + 4*s*OSTR

    // ---- W2 fragments from global (L1-hot; reloads acceptable) ----
    bf16x8 w2f[4][2];
    #pragma unroll
    for (int nt = 0; nt < 4; ++nt)
        #pragma unroll
        for (int ks = 0; ks < 2; ++ks)
            w2f[nt][ks] = *(const bf16x8*)&w2t[(nt*16 + r16) * 64 + ks*32 + q*8];

    // uniform attn weights (SGPR-pinned), per-lane bias slices
    float aw[9];
    #pragma unroll
    for (int i = 0; i < 9; ++i) {
        union { float f; int u; } c; c.f = attn9[i];
        c.u = __builtin_amdgcn_readfirstlane(c.u);
        aw[i] = c.f;
    }
    float b1c[4], b2c[4];
    #pragma unroll
    for (int nt = 0; nt < 4; ++nt) { b1c[nt] = b1[nt*16 + r16]; b2c[nt] = b2[nt*16 + r16]; }

    const int batch0 = blockIdx.x * 64 + wave * 16;

    // per-lane streaming global pointers (advance 4 batches = 768 floats per mt)
    const float* xptr = nodes + ((long)(batch0 + bA)) * 192 + iAr * 64 + q * 8;
    float*       optr = out + (long)batch0 * 192 + lane * 4;

    __syncthreads();   // W1 staged

    #pragma unroll
    for (int mt = 0; mt < 4; ++mt) {
        // ---- X -> A-frags (k = ks*32 + q*8 + e); constant offsets off xptr ----
        f32x4 x0 = *(const f32x4*)(xptr);
        f32x4 x1 = *(const f32x4*)(xptr + 4);
        f32x4 x2v = *(const f32x4*)(xptr + 32);
        f32x4 x3 = *(const f32x4*)(xptr + 36);
        bf16x8 afr0, afr1;
        #pragma unroll
        for (int e = 0; e < 4; ++e) {
            afr0[e]   = f2bs(x0[e]);  afr0[4+e] = f2bs(x1[e]);
            afr1[e]   = f2bs(x2v[e]); afr1[4+e] = f2bs(x3[e]);
        }

        // ---- GEMM1 + lane-local gelu mix; W1 frags at w1b{0,1} + const ----
        #pragma unroll
        for (int nt = 0; nt < 4; ++nt) {
            f32x4 z = {0.f, 0.f, 0.f, 0.f};
            z = __builtin_amdgcn_mfma_f32_16x16x32_bf16(afr0, *(const bf16x8*)(w1b0 + nt*1024), z, 0, 0, 0);
            z = __builtin_amdgcn_mfma_f32_16x16x32_bf16(afr1, *(const bf16x8*)(w1b1 + nt*1024), z, 0, 0, 0);
            f32x4 y = {0.f, 0.f, 0.f, 0.f};
            y = __builtin_amdgcn_mfma_f32_16x16x32_bf16(afr0, *(const bf16x8*)(w1b0 + 4096 + nt*1024), y, 0, 0, 0);
            y = __builtin_amdgcn_mfma_f32_16x16x32_bf16(afr1, *(const bf16x8*)(w1b1 + 4096 + nt*1024), y, 0, 0, 0);

            // lane holds batch q: u rows z[0..2], v rows y[0..2], col nt*16+r16
            float u0 = z[0] + b1c[nt], u1 = z[1] + b1c[nt], u2 = z[2] + b1c[nt];
            float gg0 = 0.f, gg1 = 0.f, gg2 = 0.f;
            #pragma unroll
            for (int j = 0; j < 3; ++j) {
                float vj = y[j];
                float gl0 = gelu_t(u0 + vj);
                float gl1 = gelu_t(u1 + vj);
                float gl2 = gelu_t(u2 + vj);
                gg0 = fmaf(aw[0*3+j], gl0, gg0);
                gg1 = fmaf(aw[1*3+j], gl1, gg1);
                gg2 = fmaf(aw[2*3+j], gl2, gg2);
            }
            gww[0 * WSTR + nt*16] = (unsigned short)f2bs(gg0);
            gww[1 * WSTR + nt*16] = (unsigned short)f2bs(gg1);
            gww[2 * WSTR + nt*16] = (unsigned short)f2bs(gg2);
        }
        // same-wave DS ordering: compiler emits lgkmcnt before dependent reads

        // ---- GEMM2: A = G via LDS transpose (base + const), B = W2 in regs ----
        bf16x8 gfr0 = *(const bf16x8*)(gfrb);
        bf16x8 gfr1 = *(const bf16x8*)(gfrb + 32);
        #pragma unroll
        for (int nt = 0; nt < 4; ++nt) {
            f32x4 acc = {0.f, 0.f, 0.f, 0.f};
            acc = __builtin_amdgcn_mfma_f32_16x16x32_bf16(gfr0, w2f[nt][0], acc, 0, 0, 0);
            acc = __builtin_amdgcn_mfma_f32_16x16x32_bf16(gfr1, w2f[nt][1], acc, 0, 0, 0);
            // overwrites Gw bytes already consumed by gfr reads — in-order DS
            #pragma unroll
            for (int r = 0; r < 3; ++r)
                oww[r * OSTR + nt*16] = acc[r] + b2c[nt];
        }

        // ---- coalesced full-line NT stores: base + const offsets ----
        #pragma unroll
        for (int s = 0; s < 3; ++s) {
            f32x4 v = *(const f32x4*)(owr + 4 * s * OSTR);
            __builtin_nontemporal_store(v, (f32x4*)(optr + 256 * s));
        }

        xptr += 768;
        optr += 768;
    }
}

extern "C" void kernel_launch(void* const* d_in, const int* in_sizes, int n_in,
                              void* d_out, int out_size, void* d_ws, size_t ws_size,
                              hipStream_t stream)
{
    const float* nodes = (const float*)d_in[0];
    const float* W1    = (const float*)d_in[1];
    const float* b1    = (const float*)d_in[2];
    const float* W2    = (const float*)d_in[3];
    const float* b2    = (const float*)d_in[4];
    const float* ea    = (const float*)d_in[5];
    float* out = (float*)d_out;

    unsigned short* w1t = (unsigned short*)d_ws;          // 8192 shorts (w1cat)
    unsigned short* w2t = w1t + 8192;                     // 4096 shorts (w2)
    float* attn = (float*)(w2t + 4096);                   // 9 floats

    prep_k<<<48, 256, 0, stream>>>(W1, W2, ea, w1t, w2t, attn);

    const int groups = (out_size / 64) / 3 / 64;          // 4096 blocks of 64 batches
    edge_mfma18<<<groups, 256, 0, stream>>>(nodes, w1t, w2t, attn, b1, b2, out);
}

// Round 24
// 81.052 us; speedup vs baseline: 1.0199x; 1.0102x over previous
//
#include <hip/hip_runtime.h>
#include <hip/hip_bf16.h>
#include <math.h>

typedef __attribute__((ext_vector_type(8))) short bf16x8;
typedef __attribute__((ext_vector_type(4))) float f32x4;

#define WSTR 68     // G-buffer row stride in shorts (136B): conflict-free frag reads
#define OSTR 80     // out-stage row stride in floats: 3*80 % 32 == 16 -> 2-way (free)

__device__ __forceinline__ short f2bs(float f) {   // fp32 -> bf16 RNE via hw cvt
    union { __hip_bfloat16 b; short s; } u;
    u.b = __float2bfloat16(f);
    return u.s;
}

__device__ __forceinline__ unsigned short f2b_int(float f) {  // prep path (cold)
    union { float f; unsigned int u; } x; x.f = f;
    unsigned int r = x.u + 0x7FFFu + ((x.u >> 16) & 1u);
    return (unsigned short)(r >> 16);
}

// gelu(x) = x*sigmoid(2y), y = 0.7978845608*x*(1+0.044715*x^2)   (tanh-form, hw exp2)
__device__ __forceinline__ float gelu_t(float x) {
    float x2 = x * x;
    float z  = x * fmaf(0.10294324f, x2, 2.3022082f);
    float e  = __builtin_amdgcn_exp2f(z);
    float r  = __builtin_amdgcn_rcpf(1.0f + e);
    return fmaf(x, -r, x);          // x*(1-r)
}

// prep: w1t[n*64+k] = W1cat[k][n]  (n<64: W1top col n, n>=64: W1bot col n-64)
//       w2t[n*64+k] = W2[k][n];  attn = softmax(edge_attn) rows
__global__ void prep_k(const float* __restrict__ W1, const float* __restrict__ W2,
                       const float* __restrict__ ea, unsigned short* __restrict__ w1t,
                       unsigned short* __restrict__ w2t, float* __restrict__ attn)
{
    int gid = blockIdx.x * 256 + threadIdx.x;
    if (gid < 128 * 64) {
        int n = gid >> 6, k = gid & 63;
        float v = (n < 64) ? W1[k * 64 + n] : W1[(64 + k) * 64 + (n - 64)];
        w1t[gid] = f2b_int(v);
    } else if (gid < 12288) {
        int idx = gid - 8192;
        int n = idx >> 6, k = idx & 63;
        w2t[idx] = f2b_int(W2[k * 64 + n]);
    }
    if (gid < 9) {
        int i = gid / 3, j = gid % 3;
        float e0 = ea[i*3+0], e1 = ea[i*3+1], e2 = ea[i*3+2];
        float mx = fmaxf(e0, fmaxf(e1, e2));
        float d = expf(e0-mx) + expf(e1-mx) + expf(e2-mx);
        attn[gid] = expf(ea[i*3+j] - mx) / d;
    }
}

__global__ __launch_bounds__(256, 3)
void edge_mfma19(const float* __restrict__ nodes,
                 const unsigned short* __restrict__ w1t,   // 8192 shorts
                 const unsigned short* __restrict__ w2t,   // 4096 shorts
                 const float* __restrict__ attn9,
                 const float* __restrict__ b1,
                 const float* __restrict__ b2,
                 float* __restrict__ out)
{
    __shared__ __align__(16) unsigned short Ws[8192];   // 16 KB swizzled W1
    __shared__ __align__(16) float Un[4 * 1536];        // 24 KB: per-wave 6144B region
    // per-wave region layout (bytes): G0 [0,2176) | Ow [0,3840) | G1 [3840,6016)
    // DS order per pair: writes G0,G1 -> read G0 -> write Ow (clobbers G0 only)
    //   -> read G1 -> write Ow -> store-reads. Per-wave in-order DS makes this safe.
    // total LDS 40960B -> 4 blocks/CU.

    const int t = threadIdx.x;
    const int lane = t & 63, wave = t >> 6;
    const int q = lane >> 4, r16 = lane & 15;
    float*          wb  = Un + wave * 1536;             // wave-private region
    unsigned short* G0  = (unsigned short*)wb;          // 1088 shorts
    unsigned short* G1  = (unsigned short*)(wb + 960);  // bytes 3840..6016
    float*          Ow  = wb;                           // floats [0,960)

    // ---- stage W1 global -> LDS with 16B-granular XOR swizzle ----
    {
        const ulonglong2* src = (const ulonglong2*)w1t;
        ulonglong2* dst = (ulonglong2*)Ws;
        #pragma unroll
        for (int i = 0; i < 4; ++i) {
            int c = t + i * 256;                          // 1024 chunks
            int n = c >> 3, k8 = c & 7;
            dst[(c & ~7) | (k8 ^ (n & 7))] = src[c];
        }
    }

    // padded tile row r16 -> batch-in-group bA, node-row iA (iA==3 is the dummy row)
    const int bA = r16 >> 2;
    const int iA = r16 & 3;
    const int iAr = (iA == 3) ? 0 : iA;

    // loop-invariant LDS bases (all accesses = base + compile-time const)
    const int sxor = (r16 & 7) << 3;
    const unsigned short* w1b0 = Ws + r16 * 64 + ((q * 8) ^ sxor);        // ks=0
    const unsigned short* w1b1 = Ws + r16 * 64 + ((32 + q * 8) ^ sxor);   // ks=1
    const int gwoff = (q * 4) * WSTR + r16;     // G write: + m2sel + r*WSTR + nt*16
    const int groff = r16 * WSTR + q * 8;       // G read:  + m2sel + {0,32}
    float*       oww = Ow + (q * 3) * OSTR + r16;   // + r*OSTR + nt*16
    const float* owr = Ow + q * OSTR + r16 * 4;     // + 4*s*OSTR

    // ---- W2 fragments from global (L1-hot; reloads acceptable) ----
    bf16x8 w2f[4][2];
    #pragma unroll
    for (int nt = 0; nt < 4; ++nt)
        #pragma unroll
        for (int ks = 0; ks < 2; ++ks)
            w2f[nt][ks] = *(const bf16x8*)&w2t[(nt*16 + r16) * 64 + ks*32 + q*8];

    // uniform attn weights (SGPR-pinned), per-lane bias slices
    float aw[9];
    #pragma unroll
    for (int i = 0; i < 9; ++i) {
        union { float f; int u; } c; c.f = attn9[i];
        c.u = __builtin_amdgcn_readfirstlane(c.u);
        aw[i] = c.f;
    }
    float b1c[4], b2c[4];
    #pragma unroll
    for (int nt = 0; nt < 4; ++nt) { b1c[nt] = b1[nt*16 + r16]; b2c[nt] = b2[nt*16 + r16]; }

    const int batch0 = blockIdx.x * 64 + wave * 16;
    const float* xptr = nodes + ((long)(batch0 + bA)) * 192 + iAr * 64 + q * 8;
    float*       optr = out + (long)batch0 * 192 + lane * 4;

    __syncthreads();   // W1 staged

    #pragma unroll
    for (int p = 0; p < 2; ++p) {                        // mt-pairs: {0,1}, {2,3}
        // ---- X -> A-frags for both mts of the pair ----
        bf16x8 afr[2][2];
        #pragma unroll
        for (int m2 = 0; m2 < 2; ++m2) {
            const float* xp = xptr + (p*2 + m2) * 768;
            f32x4 x0 = *(const f32x4*)(xp);
            f32x4 x1 = *(const f32x4*)(xp + 4);
            f32x4 x2v = *(const f32x4*)(xp + 32);
            f32x4 x3 = *(const f32x4*)(xp + 36);
            #pragma unroll
            for (int e = 0; e < 4; ++e) {
                afr[m2][0][e]   = f2bs(x0[e]);  afr[m2][0][4+e] = f2bs(x1[e]);
                afr[m2][1][e]   = f2bs(x2v[e]); afr[m2][1][4+e] = f2bs(x3[e]);
            }
        }

        // ---- nt-outer GEMM1: W1 frags loaded ONCE per nt, used by both mts ----
        #pragma unroll
        for (int nt = 0; nt < 4; ++nt) {
            bf16x8 fu0 = *(const bf16x8*)(w1b0 + nt*1024);
            bf16x8 fu1 = *(const bf16x8*)(w1b1 + nt*1024);
            bf16x8 fv0 = *(const bf16x8*)(w1b0 + 4096 + nt*1024);
            bf16x8 fv1 = *(const bf16x8*)(w1b1 + 4096 + nt*1024);
            #pragma unroll
            for (int m2 = 0; m2 < 2; ++m2) {
                f32x4 z = {0.f, 0.f, 0.f, 0.f};
                z = __builtin_amdgcn_mfma_f32_16x16x32_bf16(afr[m2][0], fu0, z, 0, 0, 0);
                z = __builtin_amdgcn_mfma_f32_16x16x32_bf16(afr[m2][1], fu1, z, 0, 0, 0);
                f32x4 y = {0.f, 0.f, 0.f, 0.f};
                y = __builtin_amdgcn_mfma_f32_16x16x32_bf16(afr[m2][0], fv0, y, 0, 0, 0);
                y = __builtin_amdgcn_mfma_f32_16x16x32_bf16(afr[m2][1], fv1, y, 0, 0, 0);

                float u0 = z[0] + b1c[nt], u1 = z[1] + b1c[nt], u2 = z[2] + b1c[nt];
                float gg0 = 0.f, gg1 = 0.f, gg2 = 0.f;
                #pragma unroll
                for (int j = 0; j < 3; ++j) {
                    float vj = y[j];
                    float gl0 = gelu_t(u0 + vj);
                    float gl1 = gelu_t(u1 + vj);
                    float gl2 = gelu_t(u2 + vj);
                    gg0 = fmaf(aw[0*3+j], gl0, gg0);
                    gg1 = fmaf(aw[1*3+j], gl1, gg1);
                    gg2 = fmaf(aw[2*3+j], gl2, gg2);
                }
                unsigned short* Gm = (m2 == 0) ? G0 : G1;
                Gm[gwoff + 0*WSTR + nt*16] = (unsigned short)f2bs(gg0);
                Gm[gwoff + 1*WSTR + nt*16] = (unsigned short)f2bs(gg1);
                Gm[gwoff + 2*WSTR + nt*16] = (unsigned short)f2bs(gg2);
            }
        }
        // same-wave DS ordering: compiler emits lgkmcnt before dependent reads

        // ---- GEMM2 + staged store per mt of the pair ----
        #pragma unroll
        for (int m2 = 0; m2 < 2; ++m2) {
            const unsigned short* Gm = (m2 == 0) ? G0 : G1;
            bf16x8 gfr0 = *(const bf16x8*)(Gm + groff);
            bf16x8 gfr1 = *(const bf16x8*)(Gm + groff + 32);
            #pragma unroll
            for (int nt = 0; nt < 4; ++nt) {
                f32x4 acc = {0.f, 0.f, 0.f, 0.f};
                acc = __builtin_amdgcn_mfma_f32_16x16x32_bf16(gfr0, w2f[nt][0], acc, 0, 0, 0);
                acc = __builtin_amdgcn_mfma_f32_16x16x32_bf16(gfr1, w2f[nt][1], acc, 0, 0, 0);
                #pragma unroll
                for (int r = 0; r < 3; ++r)
                    oww[r * OSTR + nt*16] = acc[r] + b2c[nt];   // Ow clobbers G0 only
            }
            // coalesced full-line NT stores: 768 consecutive floats
            float* ob = optr + (p*2 + m2) * 768;
            #pragma unroll
            for (int s = 0; s < 3; ++s) {
                f32x4 v = *(const f32x4*)(owr + 4 * s * OSTR);
                __builtin_nontemporal_store(v, (f32x4*)(ob + 256 * s));
            }
        }
    }
}

extern "C" void kernel_launch(void* const* d_in, const int* in_sizes, int n_in,
                              void* d_out, int out_size, void* d_ws, size_t ws_size,
                              hipStream_t stream)
{
    const float* nodes = (const float*)d_in[0];
    const float* W1    = (const float*)d_in[1];
    const float* b1    = (const float*)d_in[2];
    const float* W2    = (const float*)d_in[3];
    const float* b2    = (const float*)d_in[4];
    const float* ea    = (const float*)d_in[5];
    float* out = (float*)d_out;

    unsigned short* w1t = (unsigned short*)d_ws;          // 8192 shorts (w1cat)
    unsigned short* w2t = w1t + 8192;                     // 4096 shorts (w2)
    float* attn = (float*)(w2t + 4096);                   // 9 floats

    prep_k<<<48, 256, 0, stream>>>(W1, W2, ea, w1t, w2t, attn);

    const int groups = (out_size / 64) / 3 / 64;          // 4096 blocks of 64 batches
    edge_mfma19<<<groups, 256, 0, stream>>>(nodes, w1t, w2t, attn, b1, b2, out);
}

// Round 25
// 80.036 us; speedup vs baseline: 1.0329x; 1.0127x over previous
//
#include <hip/hip_runtime.h>
#include <hip/hip_bf16.h>
#include <math.h>

typedef __attribute__((ext_vector_type(8))) short bf16x8;
typedef __attribute__((ext_vector_type(4))) float f32x4;

#define WSTR 68     // G-buffer row stride in shorts (136B): conflict-free frag reads
#define OSTR 80     // out-stage row stride in floats: 3*80 % 32 == 16 -> 2-way (free)

__device__ __forceinline__ short f2bs(float f) {   // fp32 -> bf16 RNE via hw cvt
    union { __hip_bfloat16 b; short s; } u;
    u.b = __float2bfloat16(f);
    return u.s;
}

__device__ __forceinline__ unsigned short f2b_int(float f) {  // prep path (cold)
    union { float f; unsigned int u; } x; x.f = f;
    unsigned int r = x.u + 0x7FFFu + ((x.u >> 16) & 1u);
    return (unsigned short)(r >> 16);
}

// gelu(x) = x*sigmoid(2y), y = 0.7978845608*x*(1+0.044715*x^2)   (tanh-form, hw exp2)
__device__ __forceinline__ float gelu_t(float x) {
    float x2 = x * x;
    float z  = x * fmaf(0.10294324f, x2, 2.3022082f);
    float e  = __builtin_amdgcn_exp2f(z);
    float r  = __builtin_amdgcn_rcpf(1.0f + e);
    return fmaf(x, -r, x);          // x*(1-r)
}

// prep: w1t[n*64+k] = W1cat[k][n]  (n<64: W1top col n, n>=64: W1bot col n-64)
//       w2t[n*64+k] = W2[k][n];  attn = softmax(edge_attn) rows
__global__ void prep_k(const float* __restrict__ W1, const float* __restrict__ W2,
                       const float* __restrict__ ea, unsigned short* __restrict__ w1t,
                       unsigned short* __restrict__ w2t, float* __restrict__ attn)
{
    int gid = blockIdx.x * 256 + threadIdx.x;
    if (gid < 128 * 64) {
        int n = gid >> 6, k = gid & 63;
        float v = (n < 64) ? W1[k * 64 + n] : W1[(64 + k) * 64 + (n - 64)];
        w1t[gid] = f2b_int(v);
    } else if (gid < 12288) {
        int idx = gid - 8192;
        int n = idx >> 6, k = idx & 63;
        w2t[idx] = f2b_int(W2[k * 64 + n]);
    }
    if (gid < 9) {
        int i = gid / 3, j = gid % 3;
        float e0 = ea[i*3+0], e1 = ea[i*3+1], e2 = ea[i*3+2];
        float mx = fmaxf(e0, fmaxf(e1, e2));
        float d = expf(e0-mx) + expf(e1-mx) + expf(e2-mx);
        attn[gid] = expf(ea[i*3+j] - mx) / d;
    }
}

// W1 fragment from swizzled LDS tile: row in [0,128), 16B-granular XOR swizzle
#define WFRAG(Ws, row, ks) \
    (*(const bf16x8*)&(Ws)[(row) * 64 + ((((ks)*32) + q*8) ^ (((row) & 7) << 3))])

__global__ __launch_bounds__(256, 3)
void edge_mfma20(const float* __restrict__ nodes,
                 const unsigned short* __restrict__ w1t,   // 8192 shorts
                 const unsigned short* __restrict__ w2t,   // 4096 shorts
                 const float* __restrict__ attn9,
                 const float* __restrict__ b1,
                 const float* __restrict__ b2,
                 float* __restrict__ out)
{
    __shared__ __align__(16) unsigned short Ws[8192];   // 16 KB swizzled W1
    __shared__ __align__(16) float Un[4 * 12 * OSTR];   // 15.36 KB: Gw/Ow time-share union
    // total 31744 B -> 5 blocks/CU. Per-wave in-order DS pipe makes the overlay safe.

    const int t = threadIdx.x;
    const int lane = t & 63, wave = t >> 6;
    const int q = lane >> 4, r16 = lane & 15;
    float*          Ow = Un + wave * 12 * OSTR;          // wave-private
    unsigned short* Gw = (unsigned short*)Ow;            // aliased, same bytes

    // ---- stage W1 global -> LDS with 16B-granular XOR swizzle ----
    {
        const ulonglong2* src = (const ulonglong2*)w1t;
        ulonglong2* dst = (ulonglong2*)Ws;
        #pragma unroll
        for (int i = 0; i < 4; ++i) {
            int c = t + i * 256;                          // 1024 chunks
            int n = c >> 3, k8 = c & 7;
            dst[(c & ~7) | (k8 ^ (n & 7))] = src[c];
        }
    }

    // padded tile row r16 -> batch-in-group bA, node-row iA (iA==3 is the dummy row)
    const int bA = r16 >> 2;
    const int iA = r16 & 3;
    const int iAr = (iA == 3) ? 0 : iA;

    // ---- W2 fragments from global (L1-hot; reloads acceptable) ----
    bf16x8 w2f[4][2];
    #pragma unroll
    for (int nt = 0; nt < 4; ++nt)
        #pragma unroll
        for (int ks = 0; ks < 2; ++ks)
            w2f[nt][ks] = *(const bf16x8*)&w2t[(nt*16 + r16) * 64 + ks*32 + q*8];

    // uniform attn weights (SGPR-pinned), per-lane bias slices
    float aw[9];
    #pragma unroll
    for (int i = 0; i < 9; ++i) {
        union { float f; int u; } c; c.f = attn9[i];
        c.u = __builtin_amdgcn_readfirstlane(c.u);
        aw[i] = c.f;
    }
    float b1c[4], b2c[4];
    #pragma unroll
    for (int nt = 0; nt < 4; ++nt) { b1c[nt] = b1[nt*16 + r16]; b2c[nt] = b2[nt*16 + r16]; }

    const int batch0 = blockIdx.x * 64 + wave * 16;

    __syncthreads();   // W1 staged

    #pragma unroll
    for (int mt = 0; mt < 4; ++mt) {
        const int bb = batch0 + mt * 4;                   // this iter's 4 batches

        // ---- X -> A-frags straight from global (k = ks*32 + q*8 + e) ----
        const long rowA = ((long)(bb + bA)) * 3 + iAr;
        const f32x4* xp = (const f32x4*)(nodes + rowA * 64 + q * 8);
        f32x4 x0 = xp[0], x1 = xp[1], x2v = xp[8], x3 = xp[9];
        bf16x8 afr0, afr1;
        #pragma unroll
        for (int e = 0; e < 4; ++e) {
            afr0[e]   = f2bs(x0[e]);  afr0[4+e] = f2bs(x1[e]);
            afr1[e]   = f2bs(x2v[e]); afr1[4+e] = f2bs(x3[e]);
        }

        // ---- GEMM1 + lane-local gelu mix; MFMA cluster under setprio(1) ----
        // T5: no intra-loop barriers -> co-resident waves drift into different
        // phases; raising prio while this wave is in its MFMA/DS-critical
        // section lets it pre-empt waves issuing long-latency VMEM.
        #pragma unroll
        for (int nt = 0; nt < 4; ++nt) {
            __builtin_amdgcn_s_setprio(1);
            f32x4 z = {0.f, 0.f, 0.f, 0.f};
            z = __builtin_amdgcn_mfma_f32_16x16x32_bf16(afr0, WFRAG(Ws, nt*16 + r16, 0), z, 0, 0, 0);
            z = __builtin_amdgcn_mfma_f32_16x16x32_bf16(afr1, WFRAG(Ws, nt*16 + r16, 1), z, 0, 0, 0);
            f32x4 y = {0.f, 0.f, 0.f, 0.f};
            y = __builtin_amdgcn_mfma_f32_16x16x32_bf16(afr0, WFRAG(Ws, 64 + nt*16 + r16, 0), y, 0, 0, 0);
            y = __builtin_amdgcn_mfma_f32_16x16x32_bf16(afr1, WFRAG(Ws, 64 + nt*16 + r16, 1), y, 0, 0, 0);
            __builtin_amdgcn_s_setprio(0);

            // lane holds batch q: u rows z[0..2], v rows y[0..2], col nt*16+r16
            float u0 = z[0] + b1c[nt], u1 = z[1] + b1c[nt], u2 = z[2] + b1c[nt];
            float gg0 = 0.f, gg1 = 0.f, gg2 = 0.f;
            #pragma unroll
            for (int j = 0; j < 3; ++j) {
                float vj = y[j];
                float gl0 = gelu_t(u0 + vj);
                float gl1 = gelu_t(u1 + vj);
                float gl2 = gelu_t(u2 + vj);
                gg0 = fmaf(aw[0*3+j], gl0, gg0);
                gg1 = fmaf(aw[1*3+j], gl1, gg1);
                gg2 = fmaf(aw[2*3+j], gl2, gg2);
            }
            Gw[(q*4 + 0) * WSTR + nt*16 + r16] = (unsigned short)f2bs(gg0);
            Gw[(q*4 + 1) * WSTR + nt*16 + r16] = (unsigned short)f2bs(gg1);
            Gw[(q*4 + 2) * WSTR + nt*16 + r16] = (unsigned short)f2bs(gg2);
        }
        // same-wave DS ordering: compiler emits lgkmcnt before dependent reads

        // ---- GEMM2: A = G via wave-private LDS transpose, B = W2 in regs ----
        __builtin_amdgcn_s_setprio(1);
        bf16x8 gfr0 = *(const bf16x8*)&Gw[r16 * WSTR + q*8];
        bf16x8 gfr1 = *(const bf16x8*)&Gw[r16 * WSTR + 32 + q*8];
        f32x4 accs[4];
        #pragma unroll
        for (int nt = 0; nt < 4; ++nt) {
            f32x4 acc = {0.f, 0.f, 0.f, 0.f};
            acc = __builtin_amdgcn_mfma_f32_16x16x32_bf16(gfr0, w2f[nt][0], acc, 0, 0, 0);
            acc = __builtin_amdgcn_mfma_f32_16x16x32_bf16(gfr1, w2f[nt][1], acc, 0, 0, 0);
            accs[nt] = acc;
        }
        __builtin_amdgcn_s_setprio(0);
        #pragma unroll
        for (int nt = 0; nt < 4; ++nt) {
            // overwrites Gw bytes already consumed by gfr reads — in-order DS
            #pragma unroll
            for (int r = 0; r < 3; ++r)
                Ow[(q*3 + r) * OSTR + nt*16 + r16] = accs[nt][r] + b2c[nt];
        }

        // ---- coalesced full-line NT stores: 768 consecutive floats per wave-iter ----
        f32x4* gbase = (f32x4*)(out + (long)bb * 192);
        #pragma unroll
        for (int s = 0; s < 3; ++s) {
            int c = lane + 64 * s;
            f32x4 v = *(const f32x4*)&Ow[(c >> 4) * OSTR + (c & 15) * 4];
            __builtin_nontemporal_store(v, gbase + c);
        }
    }
}

extern "C" void kernel_launch(void* const* d_in, const int* in_sizes, int n_in,
                              void* d_out, int out_size, void* d_ws, size_t ws_size,
                              hipStream_t stream)
{
    const float* nodes = (const float*)d_in[0];
    const float* W1    = (const float*)d_in[1];
    const float* b1    = (const float*)d_in[2];
    const float* W2    = (const float*)d_in[3];
    const float* b2    = (const float*)d_in[4];
    const float* ea    = (const float*)d_in[5];
    float* out = (float*)d_out;

    unsigned short* w1t = (unsigned short*)d_ws;          // 8192 shorts (w1cat)
    unsigned short* w2t = w1t + 8192;                     // 4096 shorts (w2)
    float* attn = (float*)(w2t + 4096);                   // 9 floats

    prep_k<<<48, 256, 0, stream>>>(W1, W2, ea, w1t, w2t, attn);

    const int groups = (out_size / 64) / 3 / 64;          // 4096 blocks of 64 batches
    edge_mfma20<<<groups, 256, 0, stream>>>(nodes, w1t, w2t, attn, b1, b2, out);
}